// Round 18
// baseline (105.414 us; speedup 1.0000x reference)
//
#include <hip/hip_runtime.h>
#include <stdint.h>

// Problem constants
#define SEQ   2048
#define EMB   1024
#define PROJ  1024
#define HEADS 16
#define HD    64
#define BATCH 2
#define MROWS (BATCH * SEQ)   // 4096
#define QKVN  3072            // fused QKV output width

typedef __attribute__((ext_vector_type(8))) __bf16 bf16x8;
typedef __attribute__((ext_vector_type(4))) __bf16 bf16x4;
typedef __attribute__((ext_vector_type(4))) float  f32x4;

static __device__ __forceinline__ __bf16 f2b(float f) {
  union { float f; uint32_t u; } a; a.f = f;
  uint32_t r = a.u + 0x7FFFu + ((a.u >> 16) & 1u);
  union { uint16_t u; __bf16 b; } o; o.u = (uint16_t)(r >> 16);
  return o.b;
}

#define GLOAD_LDS16(gsrc, ldst)                                                \
  __builtin_amdgcn_global_load_lds(                                            \
      (const __attribute__((address_space(1))) void*)(gsrc),                   \
      (__attribute__((address_space(3))) void*)(ldst), 16, 0, 0)

// ---------------------------------------------------------------------------
// Fused prep: blocks [0,4096) cast X fp32->bf16 (4 elems/thread);
// blocks [4096,8192) transpose+cast the 4 weight matrices (32x32 LDS tiles).
// ---------------------------------------------------------------------------
__global__ void prep(const float* __restrict__ X,
                     const float* __restrict__ W0, const float* __restrict__ W1,
                     const float* __restrict__ W2, const float* __restrict__ W3,
                     __bf16* __restrict__ Xb,
                     __bf16* __restrict__ Tqkv, __bf16* __restrict__ To) {
  const int id = blockIdx.x;
  if (id < 4096) {
    int i = (id * 256 + threadIdx.x) * 4;
    float4 v = *reinterpret_cast<const float4*>(X + i);
    bf16x4 o;
    o[0] = f2b(v.x); o[1] = f2b(v.y); o[2] = f2b(v.z); o[3] = f2b(v.w);
    *reinterpret_cast<bf16x4*>(Xb + i) = o;
  } else {
    __shared__ float tile[32][33];
    int r = id - 4096;
    const int z = r >> 10; r &= 1023;
    const float* W; __bf16* T;
    switch (z) {
      case 0: W = W0; T = Tqkv;                       break;
      case 1: W = W1; T = Tqkv + (size_t)1024 * 1024; break;
      case 2: W = W2; T = Tqkv + (size_t)2048 * 1024; break;
      default: W = W3; T = To;                        break;
    }
    int k0 = (r & 31) * 32, n0 = (r >> 5) * 32;
    int tx = threadIdx.x & 31, ty = threadIdx.x >> 5;  // 256 thr: ty 0..7
#pragma unroll
    for (int q = ty; q < 32; q += 8)
      tile[q][tx] = W[(size_t)(k0 + q) * 1024 + n0 + tx];
    __syncthreads();
#pragma unroll
    for (int q = ty; q < 32; q += 8)
      T[(size_t)(n0 + q) * 1024 + k0 + tx] = f2b(tile[tx][q]);
  }
}

// ---------------------------------------------------------------------------
// bf16 GEMM, C = A[M,K] * Bt^T (Bt[N][K]). Tile BM x 128, BK=32,
// DOUBLE-BUFFERED with ONE barrier per K-iter (T3-min 2-phase): loads for
// tile t+1 are issued via global_load_lds at iter top, then ds_read+MFMA on
// tile t cover most of the load latency; the end-of-iter __syncthreads's
// automatic vmcnt drain is the only sync. Correct with a single barrier:
// writes to buf^1 this iter are read only next iter; reads of buf^1 ended
// before the previous barrier. All VM ops are gload_lds (no mixed-vmcnt
// hazard, r12 lesson). LDS: BM=128 -> 32KB (3 blocks/CU kept); BM=64 -> 24KB.
// Linear m97-proven fragment layout (BK=32, row*32 + g*8).
// SCALE_Q: output x 0.18033688 (= 0.125*log2e) for cols < 1024 (exp2-domain
// attention scores). VSPLIT: cols >= 2048 written TRANSPOSED into vt[..][s].
// ---------------------------------------------------------------------------
template <int BM, bool OUT_BF16, bool SCALE_Q, bool VSPLIT>
__global__ __launch_bounds__(256) void gemm_bt(const __bf16* __restrict__ A,
                                               const __bf16* __restrict__ Bt,
                                               void* __restrict__ Cout,
                                               __bf16* __restrict__ vt,
                                               int M, int N, int K) {
  constexpr int MI = BM / 32;  // m-frags per wave
  __shared__ __align__(16) __bf16 As[2][BM * 32];
  __shared__ __align__(16) __bf16 Bs[2][128 * 32];
  const int t = threadIdx.x;
  const int lane = t & 63, w = t >> 6;
  const int g = lane >> 4, l15 = lane & 15;
  const int m0 = blockIdx.x * BM, n0 = blockIdx.y * 128;
  const int wr = w >> 1, wc = w & 1;

  f32x4 acc[MI][4];
#pragma unroll
  for (int i = 0; i < MI; i++)
#pragma unroll
    for (int j = 0; j < 4; j++) acc[i][j] = {0.f, 0.f, 0.f, 0.f};

  // prologue: stage K-tile 0 into buffer 0
#pragma unroll
  for (int c = t; c < BM * 4; c += 256)
    GLOAD_LDS16(A + (size_t)(m0 + (c >> 2)) * K + (c & 3) * 8, As[0] + c * 8);
#pragma unroll
  for (int c = t; c < 512; c += 256)
    GLOAD_LDS16(Bt + (size_t)(n0 + (c >> 2)) * K + (c & 3) * 8, Bs[0] + c * 8);
  __syncthreads();  // compiler drains vmcnt before s_barrier

  const int NIT = K / 32;
  for (int it = 0; it < NIT; ++it) {
    const int cur = it & 1;
    if (it + 1 < NIT) {  // issue next tile's async loads (overlap with MFMA)
      const int k0 = (it + 1) * 32;
#pragma unroll
      for (int c = t; c < BM * 4; c += 256)
        GLOAD_LDS16(A + (size_t)(m0 + (c >> 2)) * K + k0 + (c & 3) * 8, As[cur ^ 1] + c * 8);
#pragma unroll
      for (int c = t; c < 512; c += 256)
        GLOAD_LDS16(Bt + (size_t)(n0 + (c >> 2)) * K + k0 + (c & 3) * 8, Bs[cur ^ 1] + c * 8);
    }

    bf16x8 af[MI], bfr[4];
#pragma unroll
    for (int mi = 0; mi < MI; mi++)
      af[mi] = *reinterpret_cast<const bf16x8*>(As[cur] + (wr * (BM / 2) + mi * 16 + l15) * 32 + g * 8);
#pragma unroll
    for (int ni = 0; ni < 4; ni++)
      bfr[ni] = *reinterpret_cast<const bf16x8*>(Bs[cur] + (wc * 64 + ni * 16 + l15) * 32 + g * 8);
#pragma unroll
    for (int mi = 0; mi < MI; mi++)
#pragma unroll
      for (int ni = 0; ni < 4; ni++)
        acc[mi][ni] = __builtin_amdgcn_mfma_f32_16x16x32_bf16(af[mi], bfr[ni], acc[mi][ni], 0, 0, 0);

    __syncthreads();  // drains vmcnt (next buffer staged) + all reads done
  }

#pragma unroll
  for (int mi = 0; mi < MI; mi++)
#pragma unroll
    for (int ni = 0; ni < 4; ni++) {
      int row = m0 + wr * (BM / 2) + mi * 16 + g * 4;
      int col = n0 + wc * 64 + ni * 16 + l15;
      if (VSPLIT && col >= 2048) {  // V projection -> transposed store
        int hd = col - 2048;
        int bb = row >> 11, ss = row & 2047;
        bf16x4 v4;
#pragma unroll
        for (int r = 0; r < 4; r++) v4[r] = f2b(acc[mi][ni][r]);
        *reinterpret_cast<bf16x4*>(vt + ((size_t)((bb * 16 + (hd >> 6)) * 64 + (hd & 63))) * 2048 + ss) = v4;
      } else {
#pragma unroll
        for (int r = 0; r < 4; r++) {
          float v = acc[mi][ni][r];
          if (SCALE_Q && col < 1024) v *= 0.18033688011112042f;  // 0.125*log2(e)
          if (OUT_BF16)
            ((__bf16*)Cout)[(size_t)(row + r) * N + col] = f2b(v);
          else
            ((float*)Cout)[(size_t)(row + r) * N + col] = v;
        }
      }
    }
}

// ---------------------------------------------------------------------------
// Causal flash attention, LDS-shared K/V, KVBLK=64, member-per-block.
// r16/r17 structure (best measured: 42.4us), byte-identical this round.
// Softmax in exp2 domain via __builtin_amdgcn_exp2f (raw v_exp_f32; library
// exp2f is OCML slow-path -- r15 regression). Q pre-scaled 0.125*log2e.
// Grid 1024 blocks x 256 thr (4 waves); LDS 41984B -> 3 resident blocks/CU.
// id&7 = xcd (owns 4 heads); bh = (id&7)*4 + ((id>>3)&3);
// mi = 31 - (id>>5): heavy-first LPT. Block = one 64-row member; Tm = mi+1
// KV tiles; wave w owns 16 rows qw = 64*mi+16*w; diag mask at it==Tm-1.
// K[64][64] + V^T[64][64] double-buffered in LDS (reg-staged, XOR-swizzle
// chunk^=(row&7): loads issued BEFORE compute, ds_writes after = T14 split).
// Swapped QK^T (D[kv][q], lane-local softmax, M=1). T5 setprio on MFMA.
// launch_bounds min-waves 2 (r5: 4 -> spill). r12 lesson: no global_load_lds
// prefetch mixed with same-iter vector loads; no scattered-L2 V reads.
// ---------------------------------------------------------------------------
__global__ __launch_bounds__(256, 2) void attn_fwd(const __bf16* __restrict__ QKV,
                                                   const __bf16* __restrict__ Vt,
                                                   __bf16* __restrict__ ctx) {
  const int id = blockIdx.x;
  const int bh = (id & 7) * 4 + ((id >> 3) & 3);
  const int mi = 31 - (id >> 5);                // member 0..31, heavy first
  const int b = bh >> 4, h = bh & 15;
  const int tid = threadIdx.x, lane = tid & 63, w = tid >> 6;
  const int g = lane >> 4, l15 = lane & 15;

  __shared__ __align__(16) __bf16 Ks[2][64 * 64];
  __shared__ __align__(16) __bf16 Vs[2][64 * 64];
  __shared__ __align__(16) __bf16 P_lds[4][16][72];

  const __bf16* Qg  = QKV + (size_t)b * SEQ * QKVN + h * 64;
  const __bf16* Kg  = Qg + 1024;
  const __bf16* VtH = Vt + (size_t)bh * 64 * 2048;
  __bf16* Cg = ctx + (size_t)b * SEQ * 1024 + h * 64;

  const int r0 = tid >> 3, j0 = tid & 7;
  const int r1 = r0 + 32;
  const int ls0 = r0 * 64 + ((j0 ^ (r0 & 7)) * 8);
  const int ls1 = r1 * 64 + ((j0 ^ (r1 & 7)) * 8);
  const size_t gk0 = (size_t)r0 * QKVN + j0 * 8;
  const size_t gk1 = (size_t)r1 * QKVN + j0 * 8;
  const size_t gv0 = (size_t)r0 * 2048 + j0 * 8;
  const size_t gv1 = (size_t)r1 * 2048 + j0 * 8;
  const int xw = l15 & 7;  // read-side row XOR ((nb*16+l15)&7 == l15&7)

  const int qw = mi * 64 + 16 * w;              // wave's 16 rows
  const int Tm = mi + 1;

  // Q fragments: qf[ks][j] = Q[qw+l15][ks*32+g*8+j]
  bf16x8 qf[2];
#pragma unroll
  for (int ks = 0; ks < 2; ks++)
    qf[ks] = *reinterpret_cast<const bf16x8*>(
        Qg + (size_t)(qw + l15) * QKVN + ks * 32 + g * 8);

  f32x4 acco[4];
  float mrun = -1e30f, lrun = 0.f;
#pragma unroll
  for (int nd = 0; nd < 4; nd++) acco[nd] = {0.f, 0.f, 0.f, 0.f};

  // prologue: stage tile 0 into buffer 0
  {
    bf16x8 ka = *reinterpret_cast<const bf16x8*>(Kg + gk0);
    bf16x8 kb = *reinterpret_cast<const bf16x8*>(Kg + gk1);
    bf16x8 va = *reinterpret_cast<const bf16x8*>(VtH + gv0);
    bf16x8 vc = *reinterpret_cast<const bf16x8*>(VtH + gv1);
    *reinterpret_cast<bf16x8*>(Ks[0] + ls0) = ka;
    *reinterpret_cast<bf16x8*>(Ks[0] + ls1) = kb;
    *reinterpret_cast<bf16x8*>(Vs[0] + ls0) = va;
    *reinterpret_cast<bf16x8*>(Vs[0] + ls1) = vc;
  }
  __syncthreads();

  for (int it = 0; it < Tm; ++it) {
    const int cur = it & 1, nxt = cur ^ 1;
    const bool hn = (it + 1 < Tm);
    bf16x8 ka, kb, va, vc;
    if (hn) {  // issue next tile's loads early (T14 split)
      const size_t kvn = (size_t)(it + 1) * 64;
      ka = *reinterpret_cast<const bf16x8*>(Kg + kvn * QKVN + gk0);
      kb = *reinterpret_cast<const bf16x8*>(Kg + kvn * QKVN + gk1);
      va = *reinterpret_cast<const bf16x8*>(VtH + kvn + gv0);
      vc = *reinterpret_cast<const bf16x8*>(VtH + kvn + gv1);
    }

    {
      const int kv0 = it * 64;
      const bool diag = (it == Tm - 1);
      const __bf16* Kc = Ks[cur];
      const __bf16* Vc = Vs[cur];

      // fragments from LDS (swizzled)
      bf16x8 kf[4][2], vb[4][2];
#pragma unroll
      for (int nb = 0; nb < 4; nb++) {
        const int row = (nb * 16 + l15) * 64;
#pragma unroll
        for (int ks = 0; ks < 2; ks++) {
          const int co = ((ks * 4 + g) ^ xw) * 8;
          kf[nb][ks] = *reinterpret_cast<const bf16x8*>(Kc + row + co);
          vb[nb][ks] = *reinterpret_cast<const bf16x8*>(Vc + row + co);
        }
      }

      // ---- QK^T (swapped): accS[nb], D[kv][q], q = qw+l15
      f32x4 accS[4];
#pragma unroll
      for (int nb = 0; nb < 4; nb++) accS[nb] = {0.f, 0.f, 0.f, 0.f};
      __builtin_amdgcn_s_setprio(1);
#pragma unroll
      for (int nb = 0; nb < 4; nb++) {
        accS[nb] = __builtin_amdgcn_mfma_f32_16x16x32_bf16(kf[nb][0], qf[0], accS[nb], 0, 0, 0);
        accS[nb] = __builtin_amdgcn_mfma_f32_16x16x32_bf16(kf[nb][1], qf[1], accS[nb], 0, 0, 0);
      }
      __builtin_amdgcn_s_setprio(0);

      // ---- causal mask (diagonal tile only)
      if (diag) {
        const int qi = qw + l15;
#pragma unroll
        for (int nb = 0; nb < 4; nb++)
#pragma unroll
          for (int r = 0; r < 4; r++) {
            int kvi = kv0 + nb * 16 + g * 4 + r;
            if (kvi > qi) accS[nb][r] = -1e30f;
          }
      }

      // ---- online softmax (exp2 domain, raw v_exp_f32), defer-max
      {
        float a0 = fmaxf(fmaxf(accS[0][0], accS[0][1]), accS[0][2]);
        float a1 = fmaxf(fmaxf(accS[0][3], accS[1][0]), accS[1][1]);
        float a2 = fmaxf(fmaxf(accS[1][2], accS[1][3]), accS[2][0]);
        float a3 = fmaxf(fmaxf(accS[2][1], accS[2][2]), accS[2][3]);
        float a4 = fmaxf(fmaxf(accS[3][0], accS[3][1]), accS[3][2]);
        float pmax = fmaxf(fmaxf(fmaxf(a0, a1), a2),
                           fmaxf(fmaxf(a3, a4), accS[3][3]));
        pmax = fmaxf(pmax, __shfl_xor(pmax, 16));
        pmax = fmaxf(pmax, __shfl_xor(pmax, 32));
        if (!__all(pmax <= mrun + 11.5416f)) {  // 8 * log2(e)
          float mnew = fmaxf(mrun, pmax);
          float corr = __builtin_amdgcn_exp2f(mrun - mnew);
          mrun = mnew;
          lrun *= corr;
#pragma unroll
          for (int r = 0; r < 4; r++) {
            float cr = __shfl(corr, (g << 4) + (g << 2) + r);
#pragma unroll
            for (int nd = 0; nd < 4; nd++) acco[nd][r] *= cr;
          }
        }
        float lsum = 0.f;
#pragma unroll
        for (int nb = 0; nb < 4; nb++) {
          bf16x4 pk;
#pragma unroll
          for (int r = 0; r < 4; r++) {
            float pv = __builtin_amdgcn_exp2f(accS[nb][r] - mrun);
            lsum += pv;
            pk[r] = (__bf16)pv;
          }
          *reinterpret_cast<bf16x4*>(&P_lds[w][l15][nb * 16 + g * 4]) = pk;
        }
        lsum += __shfl_xor(lsum, 16);
        lsum += __shfl_xor(lsum, 32);
        lrun += lsum;
      }

      // ---- PV: O[q][d] += P[q][kv] * V[kv][d]
      {
        bf16x8 pa0 = *reinterpret_cast<const bf16x8*>(&P_lds[w][l15][g * 8]);
        bf16x8 pa1 = *reinterpret_cast<const bf16x8*>(&P_lds[w][l15][32 + g * 8]);
        __builtin_amdgcn_s_setprio(1);
#pragma unroll
        for (int nd = 0; nd < 4; nd++) {
          acco[nd] = __builtin_amdgcn_mfma_f32_16x16x32_bf16(pa0, vb[nd][0], acco[nd], 0, 0, 0);
          acco[nd] = __builtin_amdgcn_mfma_f32_16x16x32_bf16(pa1, vb[nd][1], acco[nd], 0, 0, 0);
        }
        __builtin_amdgcn_s_setprio(0);
      }
    }

    if (hn) {  // write staged regs to the other buffer
      *reinterpret_cast<bf16x8*>(Ks[nxt] + ls0) = ka;
      *reinterpret_cast<bf16x8*>(Ks[nxt] + ls1) = kb;
      *reinterpret_cast<bf16x8*>(Vs[nxt] + ls0) = va;
      *reinterpret_cast<bf16x8*>(Vs[nxt] + ls1) = vc;
    }
    __syncthreads();
  }

  // epilogue: ctx = O / l for this wave's 16 rows
  {
    float inv = 1.0f / lrun;
#pragma unroll
    for (int r = 0; r < 4; r++) {
      float ir = __shfl(inv, (g << 4) + (g << 2) + r);
      int qrow = qw + g * 4 + r;
#pragma unroll
      for (int nd = 0; nd < 4; nd++)
        Cg[(size_t)qrow * 1024 + nd * 16 + l15] = (__bf16)(acco[nd][r] * ir);
    }
  }
}

// ---------------------------------------------------------------------------
extern "C" void kernel_launch(void* const* d_in, const int* in_sizes, int n_in,
                              void* d_out, int out_size, void* d_ws, size_t ws_size,
                              hipStream_t stream) {
  const float* X  = (const float*)d_in[0];
  const float* Wq = (const float*)d_in[1];
  const float* Wk = (const float*)d_in[2];
  const float* Wv = (const float*)d_in[3];
  const float* Wo = (const float*)d_in[4];
  float* out = (float*)d_out;

  uint8_t* ws = (uint8_t*)d_ws;
  size_t off = 0;
  const size_t actBytes = (size_t)MROWS * 1024 * 2;          // 8 MB
  __bf16* Xb    = (__bf16*)(ws + off); off += actBytes;      // freed after QKV gemm
  __bf16* WqkvT = (__bf16*)(ws + off); off += (size_t)QKVN * 1024 * 2;
  __bf16* WoT   = (__bf16*)(ws + off); off += (size_t)1024 * 1024 * 2;
  __bf16* QKV   = (__bf16*)(ws + off); off += (size_t)MROWS * QKVN * 2;
  __bf16* Vt    = (__bf16*)(ws + off); off += actBytes;
  __bf16* Cb    = Xb;  // alias: X dead after QKV projection

  // 1) fused cast + weight transpose
  prep<<<dim3(8192), dim3(256), 0, stream>>>(X, Wq, Wk, Wv, Wo, Xb, WqkvT, WoT);

  // 2) fused QKV projection (Q pre-scaled by 0.125*log2e; V transposed to Vt)
  gemm_bt<128, true, true, true><<<dim3(MROWS / 128, QKVN / 128), dim3(256), 0, stream>>>(
      Xb, WqkvT, QKV, Vt, MROWS, QKVN, EMB);

  // 3) causal flash attention (LDS-shared K/V, member-per-block, heavy-first)
  attn_fwd<<<dim3(1024), dim3(256), 0, stream>>>(QKV, Vt, Cb);

  // 4) output projection (fp32 out), 64x128 tiles (512 blocks, 2/CU)
  gemm_bt<64, false, false, false><<<dim3(MROWS / 64, PROJ / 128), dim3(256), 0, stream>>>(
      Cb, WoT, out, nullptr, MROWS, PROJ, PROJ);
}

// Round 19
// 100.015 us; speedup vs baseline: 1.0540x; 1.0540x over previous
//
#include <hip/hip_runtime.h>
#include <stdint.h>

// Problem constants
#define SEQ   2048
#define EMB   1024
#define PROJ  1024
#define HEADS 16
#define HD    64
#define BATCH 2
#define MROWS (BATCH * SEQ)   // 4096
#define QKVN  3072            // fused QKV output width

typedef __attribute__((ext_vector_type(8))) __bf16 bf16x8;
typedef __attribute__((ext_vector_type(4))) __bf16 bf16x4;
typedef __attribute__((ext_vector_type(4))) float  f32x4;

static __device__ __forceinline__ __bf16 f2b(float f) {
  union { float f; uint32_t u; } a; a.f = f;
  uint32_t r = a.u + 0x7FFFu + ((a.u >> 16) & 1u);
  union { uint16_t u; __bf16 b; } o; o.u = (uint16_t)(r >> 16);
  return o.b;
}

#define GLOAD_LDS16(gsrc, ldst)                                                \
  __builtin_amdgcn_global_load_lds(                                            \
      (const __attribute__((address_space(1))) void*)(gsrc),                   \
      (__attribute__((address_space(3))) void*)(ldst), 16, 0, 0)

// ---------------------------------------------------------------------------
// Fused prep: blocks [0,4096) cast X fp32->bf16 (4 elems/thread);
// blocks [4096,8192) transpose+cast the 4 weight matrices (32x32 LDS tiles).
// ---------------------------------------------------------------------------
__global__ void prep(const float* __restrict__ X,
                     const float* __restrict__ W0, const float* __restrict__ W1,
                     const float* __restrict__ W2, const float* __restrict__ W3,
                     __bf16* __restrict__ Xb,
                     __bf16* __restrict__ Tqkv, __bf16* __restrict__ To) {
  const int id = blockIdx.x;
  if (id < 4096) {
    int i = (id * 256 + threadIdx.x) * 4;
    float4 v = *reinterpret_cast<const float4*>(X + i);
    bf16x4 o;
    o[0] = f2b(v.x); o[1] = f2b(v.y); o[2] = f2b(v.z); o[3] = f2b(v.w);
    *reinterpret_cast<bf16x4*>(Xb + i) = o;
  } else {
    __shared__ float tile[32][33];
    int r = id - 4096;
    const int z = r >> 10; r &= 1023;
    const float* W; __bf16* T;
    switch (z) {
      case 0: W = W0; T = Tqkv;                       break;
      case 1: W = W1; T = Tqkv + (size_t)1024 * 1024; break;
      case 2: W = W2; T = Tqkv + (size_t)2048 * 1024; break;
      default: W = W3; T = To;                        break;
    }
    int k0 = (r & 31) * 32, n0 = (r >> 5) * 32;
    int tx = threadIdx.x & 31, ty = threadIdx.x >> 5;  // 256 thr: ty 0..7
#pragma unroll
    for (int q = ty; q < 32; q += 8)
      tile[q][tx] = W[(size_t)(k0 + q) * 1024 + n0 + tx];
    __syncthreads();
#pragma unroll
    for (int q = ty; q < 32; q += 8)
      T[(size_t)(n0 + q) * 1024 + k0 + tx] = f2b(tile[tx][q]);
  }
}

// ---------------------------------------------------------------------------
// bf16 GEMM, C = A[M,K] * Bt^T (Bt[N][K]). Tile BM x 128, BK=64.
// 256 thr = 4 waves in 2x2; wave tile (BM/2) x 64. MFMA 16x16x32.
// BK=64 single-buffer is the measured optimum (r15: -5.3us vs BK=32;
// r18: explicit dbuf/1-barrier = +4.3us REGRESSION -- the in-order vmcnt
// drains at every barrier regardless, per m99/m131-m141; implicit
// multi-block overlap already hides the load latency).
// Staging PRE-SWIZZLES the global k-column (j ^= row&7, rule #21/m173) and
// the read applies the same XOR -- full 32-bank spread.
// SCALE_Q: output x 0.18033688 (= 0.125 * log2(e)) for cols < 1024: attention
// scores land in the exp2 domain.
// VSPLIT: cols >= 2048 (V projection) written TRANSPOSED into vt[..][s].
// ---------------------------------------------------------------------------
template <int BM, bool OUT_BF16, bool SCALE_Q, bool VSPLIT>
__global__ __launch_bounds__(256) void gemm_bt(const __bf16* __restrict__ A,
                                               const __bf16* __restrict__ Bt,
                                               void* __restrict__ Cout,
                                               __bf16* __restrict__ vt,
                                               int M, int N, int K) {
  constexpr int MI = BM / 32;  // m-frags per wave
  __shared__ __align__(16) __bf16 As[BM * 64];
  __shared__ __align__(16) __bf16 Bs[128 * 64];
  const int t = threadIdx.x;
  const int lane = t & 63, w = t >> 6;
  const int g = lane >> 4, l15 = lane & 15;
  const int m0 = blockIdx.x * BM, n0 = blockIdx.y * 128;
  const int wr = w >> 1, wc = w & 1;
  const int xg = l15 & 7;  // read-side row XOR ((..+mi*16+l15)&7 == l15&7)

  f32x4 acc[MI][4];
#pragma unroll
  for (int i = 0; i < MI; i++)
#pragma unroll
    for (int j = 0; j < 4; j++) acc[i][j] = {0.f, 0.f, 0.f, 0.f};

  for (int k0 = 0; k0 < K; k0 += 64) {
    __syncthreads();
#pragma unroll
    for (int c = t; c < BM * 8; c += 256)  // A tile [BM][64], src pre-swizzled
      GLOAD_LDS16(A + (size_t)(m0 + (c >> 3)) * K + k0 + (((c & 7) ^ ((c >> 3) & 7)) * 8),
                  As + c * 8);
#pragma unroll
    for (int c = t; c < 1024; c += 256)    // Bt tile [128][64]
      GLOAD_LDS16(Bt + (size_t)(n0 + (c >> 3)) * K + k0 + (((c & 7) ^ ((c >> 3) & 7)) * 8),
                  Bs + c * 8);
    __syncthreads();

#pragma unroll
    for (int ks = 0; ks < 2; ks++) {
      bf16x8 af[MI], bfr[4];
      const int co = ((ks * 4 + g) ^ xg) * 8;
#pragma unroll
      for (int mi = 0; mi < MI; mi++)
        af[mi] = *reinterpret_cast<const bf16x8*>(As + (wr * (BM / 2) + mi * 16 + l15) * 64 + co);
#pragma unroll
      for (int ni = 0; ni < 4; ni++)
        bfr[ni] = *reinterpret_cast<const bf16x8*>(Bs + (wc * 64 + ni * 16 + l15) * 64 + co);
#pragma unroll
      for (int mi = 0; mi < MI; mi++)
#pragma unroll
        for (int ni = 0; ni < 4; ni++)
          acc[mi][ni] = __builtin_amdgcn_mfma_f32_16x16x32_bf16(af[mi], bfr[ni], acc[mi][ni], 0, 0, 0);
    }
  }

#pragma unroll
  for (int mi = 0; mi < MI; mi++)
#pragma unroll
    for (int ni = 0; ni < 4; ni++) {
      int row = m0 + wr * (BM / 2) + mi * 16 + g * 4;
      int col = n0 + wc * 64 + ni * 16 + l15;
      if (VSPLIT && col >= 2048) {  // V projection -> transposed store
        int hd = col - 2048;
        int bb = row >> 11, ss = row & 2047;
        bf16x4 v4;
#pragma unroll
        for (int r = 0; r < 4; r++) v4[r] = f2b(acc[mi][ni][r]);
        *reinterpret_cast<bf16x4*>(vt + ((size_t)((bb * 16 + (hd >> 6)) * 64 + (hd & 63))) * 2048 + ss) = v4;
      } else {
#pragma unroll
        for (int r = 0; r < 4; r++) {
          float v = acc[mi][ni][r];
          if (SCALE_Q && col < 1024) v *= 0.18033688011112042f;  // 0.125*log2(e)
          if (OUT_BF16)
            ((__bf16*)Cout)[(size_t)(row + r) * N + col] = f2b(v);
          else
            ((float*)Cout)[(size_t)(row + r) * N + col] = v;
        }
      }
    }
}

// ---------------------------------------------------------------------------
// Causal flash attention, LDS-shared K/V, KVBLK=64, member-per-block.
// Best-measured structure (r16/r17: 42.4us), byte-identical.
// Softmax in exp2 domain via __builtin_amdgcn_exp2f (raw v_exp_f32; library
// exp2f is OCML slow-path -- r15 regression). Q pre-scaled 0.125*log2e.
// Grid 1024 blocks x 256 thr (4 waves); LDS 41984B -> 3 resident blocks/CU.
// id&7 = xcd (owns 4 heads); bh = (id&7)*4 + ((id>>3)&3);
// mi = 31 - (id>>5): heavy-first LPT. Block = one 64-row member; Tm = mi+1
// KV tiles; wave w owns 16 rows qw = 64*mi+16*w; diag mask at it==Tm-1.
// K[64][64] + V^T[64][64] double-buffered in LDS (reg-staged, XOR-swizzle
// chunk^=(row&7): loads issued BEFORE compute, ds_writes after = T14 split).
// Swapped QK^T (D[kv][q], lane-local softmax, M=1). T5 setprio on MFMA.
// launch_bounds min-waves 2 (r5: 4 -> spill). r12 lesson: no global_load_lds
// prefetch mixed with same-iter vector loads; no scattered-L2 V reads.
// ---------------------------------------------------------------------------
__global__ __launch_bounds__(256, 2) void attn_fwd(const __bf16* __restrict__ QKV,
                                                   const __bf16* __restrict__ Vt,
                                                   __bf16* __restrict__ ctx) {
  const int id = blockIdx.x;
  const int bh = (id & 7) * 4 + ((id >> 3) & 3);
  const int mi = 31 - (id >> 5);                // member 0..31, heavy first
  const int b = bh >> 4, h = bh & 15;
  const int tid = threadIdx.x, lane = tid & 63, w = tid >> 6;
  const int g = lane >> 4, l15 = lane & 15;

  __shared__ __align__(16) __bf16 Ks[2][64 * 64];
  __shared__ __align__(16) __bf16 Vs[2][64 * 64];
  __shared__ __align__(16) __bf16 P_lds[4][16][72];

  const __bf16* Qg  = QKV + (size_t)b * SEQ * QKVN + h * 64;
  const __bf16* Kg  = Qg + 1024;
  const __bf16* VtH = Vt + (size_t)bh * 64 * 2048;
  __bf16* Cg = ctx + (size_t)b * SEQ * 1024 + h * 64;

  const int r0 = tid >> 3, j0 = tid & 7;
  const int r1 = r0 + 32;
  const int ls0 = r0 * 64 + ((j0 ^ (r0 & 7)) * 8);
  const int ls1 = r1 * 64 + ((j0 ^ (r1 & 7)) * 8);
  const size_t gk0 = (size_t)r0 * QKVN + j0 * 8;
  const size_t gk1 = (size_t)r1 * QKVN + j0 * 8;
  const size_t gv0 = (size_t)r0 * 2048 + j0 * 8;
  const size_t gv1 = (size_t)r1 * 2048 + j0 * 8;
  const int xw = l15 & 7;  // read-side row XOR ((nb*16+l15)&7 == l15&7)

  const int qw = mi * 64 + 16 * w;              // wave's 16 rows
  const int Tm = mi + 1;

  // Q fragments: qf[ks][j] = Q[qw+l15][ks*32+g*8+j]
  bf16x8 qf[2];
#pragma unroll
  for (int ks = 0; ks < 2; ks++)
    qf[ks] = *reinterpret_cast<const bf16x8*>(
        Qg + (size_t)(qw + l15) * QKVN + ks * 32 + g * 8);

  f32x4 acco[4];
  float mrun = -1e30f, lrun = 0.f;
#pragma unroll
  for (int nd = 0; nd < 4; nd++) acco[nd] = {0.f, 0.f, 0.f, 0.f};

  // prologue: stage tile 0 into buffer 0
  {
    bf16x8 ka = *reinterpret_cast<const bf16x8*>(Kg + gk0);
    bf16x8 kb = *reinterpret_cast<const bf16x8*>(Kg + gk1);
    bf16x8 va = *reinterpret_cast<const bf16x8*>(VtH + gv0);
    bf16x8 vc = *reinterpret_cast<const bf16x8*>(VtH + gv1);
    *reinterpret_cast<bf16x8*>(Ks[0] + ls0) = ka;
    *reinterpret_cast<bf16x8*>(Ks[0] + ls1) = kb;
    *reinterpret_cast<bf16x8*>(Vs[0] + ls0) = va;
    *reinterpret_cast<bf16x8*>(Vs[0] + ls1) = vc;
  }
  __syncthreads();

  for (int it = 0; it < Tm; ++it) {
    const int cur = it & 1, nxt = cur ^ 1;
    const bool hn = (it + 1 < Tm);
    bf16x8 ka, kb, va, vc;
    if (hn) {  // issue next tile's loads early (T14 split)
      const size_t kvn = (size_t)(it + 1) * 64;
      ka = *reinterpret_cast<const bf16x8*>(Kg + kvn * QKVN + gk0);
      kb = *reinterpret_cast<const bf16x8*>(Kg + kvn * QKVN + gk1);
      va = *reinterpret_cast<const bf16x8*>(VtH + kvn + gv0);
      vc = *reinterpret_cast<const bf16x8*>(VtH + kvn + gv1);
    }

    {
      const int kv0 = it * 64;
      const bool diag = (it == Tm - 1);
      const __bf16* Kc = Ks[cur];
      const __bf16* Vc = Vs[cur];

      // fragments from LDS (swizzled)
      bf16x8 kf[4][2], vb[4][2];
#pragma unroll
      for (int nb = 0; nb < 4; nb++) {
        const int row = (nb * 16 + l15) * 64;
#pragma unroll
        for (int ks = 0; ks < 2; ks++) {
          const int co = ((ks * 4 + g) ^ xw) * 8;
          kf[nb][ks] = *reinterpret_cast<const bf16x8*>(Kc + row + co);
          vb[nb][ks] = *reinterpret_cast<const bf16x8*>(Vc + row + co);
        }
      }

      // ---- QK^T (swapped): accS[nb], D[kv][q], q = qw+l15
      f32x4 accS[4];
#pragma unroll
      for (int nb = 0; nb < 4; nb++) accS[nb] = {0.f, 0.f, 0.f, 0.f};
      __builtin_amdgcn_s_setprio(1);
#pragma unroll
      for (int nb = 0; nb < 4; nb++) {
        accS[nb] = __builtin_amdgcn_mfma_f32_16x16x32_bf16(kf[nb][0], qf[0], accS[nb], 0, 0, 0);
        accS[nb] = __builtin_amdgcn_mfma_f32_16x16x32_bf16(kf[nb][1], qf[1], accS[nb], 0, 0, 0);
      }
      __builtin_amdgcn_s_setprio(0);

      // ---- causal mask (diagonal tile only)
      if (diag) {
        const int qi = qw + l15;
#pragma unroll
        for (int nb = 0; nb < 4; nb++)
#pragma unroll
          for (int r = 0; r < 4; r++) {
            int kvi = kv0 + nb * 16 + g * 4 + r;
            if (kvi > qi) accS[nb][r] = -1e30f;
          }
      }

      // ---- online softmax (exp2 domain, raw v_exp_f32), defer-max
      {
        float a0 = fmaxf(fmaxf(accS[0][0], accS[0][1]), accS[0][2]);
        float a1 = fmaxf(fmaxf(accS[0][3], accS[1][0]), accS[1][1]);
        float a2 = fmaxf(fmaxf(accS[1][2], accS[1][3]), accS[2][0]);
        float a3 = fmaxf(fmaxf(accS[2][1], accS[2][2]), accS[2][3]);
        float a4 = fmaxf(fmaxf(accS[3][0], accS[3][1]), accS[3][2]);
        float pmax = fmaxf(fmaxf(fmaxf(a0, a1), a2),
                           fmaxf(fmaxf(a3, a4), accS[3][3]));
        pmax = fmaxf(pmax, __shfl_xor(pmax, 16));
        pmax = fmaxf(pmax, __shfl_xor(pmax, 32));
        if (!__all(pmax <= mrun + 11.5416f)) {  // 8 * log2(e)
          float mnew = fmaxf(mrun, pmax);
          float corr = __builtin_amdgcn_exp2f(mrun - mnew);
          mrun = mnew;
          lrun *= corr;
#pragma unroll
          for (int r = 0; r < 4; r++) {
            float cr = __shfl(corr, (g << 4) + (g << 2) + r);
#pragma unroll
            for (int nd = 0; nd < 4; nd++) acco[nd][r] *= cr;
          }
        }
        float lsum = 0.f;
#pragma unroll
        for (int nb = 0; nb < 4; nb++) {
          bf16x4 pk;
#pragma unroll
          for (int r = 0; r < 4; r++) {
            float pv = __builtin_amdgcn_exp2f(accS[nb][r] - mrun);
            lsum += pv;
            pk[r] = (__bf16)pv;
          }
          *reinterpret_cast<bf16x4*>(&P_lds[w][l15][nb * 16 + g * 4]) = pk;
        }
        lsum += __shfl_xor(lsum, 16);
        lsum += __shfl_xor(lsum, 32);
        lrun += lsum;
      }

      // ---- PV: O[q][d] += P[q][kv] * V[kv][d]
      {
        bf16x8 pa0 = *reinterpret_cast<const bf16x8*>(&P_lds[w][l15][g * 8]);
        bf16x8 pa1 = *reinterpret_cast<const bf16x8*>(&P_lds[w][l15][32 + g * 8]);
        __builtin_amdgcn_s_setprio(1);
#pragma unroll
        for (int nd = 0; nd < 4; nd++) {
          acco[nd] = __builtin_amdgcn_mfma_f32_16x16x32_bf16(pa0, vb[nd][0], acco[nd], 0, 0, 0);
          acco[nd] = __builtin_amdgcn_mfma_f32_16x16x32_bf16(pa1, vb[nd][1], acco[nd], 0, 0, 0);
        }
        __builtin_amdgcn_s_setprio(0);
      }
    }

    if (hn) {  // write staged regs to the other buffer
      *reinterpret_cast<bf16x8*>(Ks[nxt] + ls0) = ka;
      *reinterpret_cast<bf16x8*>(Ks[nxt] + ls1) = kb;
      *reinterpret_cast<bf16x8*>(Vs[nxt] + ls0) = va;
      *reinterpret_cast<bf16x8*>(Vs[nxt] + ls1) = vc;
    }
    __syncthreads();
  }

  // epilogue: ctx = O / l for this wave's 16 rows
  {
    float inv = 1.0f / lrun;
#pragma unroll
    for (int r = 0; r < 4; r++) {
      float ir = __shfl(inv, (g << 4) + (g << 2) + r);
      int qrow = qw + g * 4 + r;
#pragma unroll
      for (int nd = 0; nd < 4; nd++)
        Cg[(size_t)qrow * 1024 + nd * 16 + l15] = (__bf16)(acco[nd][r] * ir);
    }
  }
}

// ---------------------------------------------------------------------------
extern "C" void kernel_launch(void* const* d_in, const int* in_sizes, int n_in,
                              void* d_out, int out_size, void* d_ws, size_t ws_size,
                              hipStream_t stream) {
  const float* X  = (const float*)d_in[0];
  const float* Wq = (const float*)d_in[1];
  const float* Wk = (const float*)d_in[2];
  const float* Wv = (const float*)d_in[3];
  const float* Wo = (const float*)d_in[4];
  float* out = (float*)d_out;

  uint8_t* ws = (uint8_t*)d_ws;
  size_t off = 0;
  const size_t actBytes = (size_t)MROWS * 1024 * 2;          // 8 MB
  __bf16* Xb    = (__bf16*)(ws + off); off += actBytes;      // freed after QKV gemm
  __bf16* WqkvT = (__bf16*)(ws + off); off += (size_t)QKVN * 1024 * 2;
  __bf16* WoT   = (__bf16*)(ws + off); off += (size_t)1024 * 1024 * 2;
  __bf16* QKV   = (__bf16*)(ws + off); off += (size_t)MROWS * QKVN * 2;
  __bf16* Vt    = (__bf16*)(ws + off); off += actBytes;
  __bf16* Cb    = Xb;  // alias: X dead after QKV projection

  // 1) fused cast + weight transpose
  prep<<<dim3(8192), dim3(256), 0, stream>>>(X, Wq, Wk, Wv, Wo, Xb, WqkvT, WoT);

  // 2) fused QKV projection (Q pre-scaled by 0.125*log2e; V transposed to Vt)
  gemm_bt<128, true, true, true><<<dim3(MROWS / 128, QKVN / 128), dim3(256), 0, stream>>>(
      Xb, WqkvT, QKV, Vt, MROWS, QKVN, EMB);

  // 3) causal flash attention (LDS-shared K/V, member-per-block, heavy-first)
  attn_fwd<<<dim3(1024), dim3(256), 0, stream>>>(QKV, Vt, Cb);

  // 4) output projection (fp32 out), 64x128 tiles (512 blocks, 2/CU)
  gemm_bt<64, false, false, false><<<dim3(MROWS / 64, PROJ / 128), dim3(256), 0, stream>>>(
      Cb, WoT, out, nullptr, MROWS, PROJ, PROJ);
}

// Round 20
// 96.495 us; speedup vs baseline: 1.0924x; 1.0365x over previous
//
#include <hip/hip_runtime.h>
#include <stdint.h>

// Problem constants
#define SEQ   2048
#define EMB   1024
#define PROJ  1024
#define HEADS 16
#define HD    64
#define BATCH 2
#define MROWS (BATCH * SEQ)   // 4096
#define QKVN  3072            // fused QKV output width

typedef __attribute__((ext_vector_type(8))) __bf16 bf16x8;
typedef __attribute__((ext_vector_type(4))) __bf16 bf16x4;
typedef __attribute__((ext_vector_type(4))) float  f32x4;

static __device__ __forceinline__ __bf16 f2b(float f) {
  union { float f; uint32_t u; } a; a.f = f;
  uint32_t r = a.u + 0x7FFFu + ((a.u >> 16) & 1u);
  union { uint16_t u; __bf16 b; } o; o.u = (uint16_t)(r >> 16);
  return o.b;
}

#define GLOAD_LDS16(gsrc, ldst)                                                \
  __builtin_amdgcn_global_load_lds(                                            \
      (const __attribute__((address_space(1))) void*)(gsrc),                   \
      (__attribute__((address_space(3))) void*)(ldst), 16, 0, 0)

// ---------------------------------------------------------------------------
// Fused prep: blocks [0,4096) cast X fp32->bf16 (4 elems/thread);
// blocks [4096,8192) transpose+cast the 4 weight matrices (32x32 LDS tiles).
// ---------------------------------------------------------------------------
__global__ void prep(const float* __restrict__ X,
                     const float* __restrict__ W0, const float* __restrict__ W1,
                     const float* __restrict__ W2, const float* __restrict__ W3,
                     __bf16* __restrict__ Xb,
                     __bf16* __restrict__ Tqkv, __bf16* __restrict__ To) {
  const int id = blockIdx.x;
  if (id < 4096) {
    int i = (id * 256 + threadIdx.x) * 4;
    float4 v = *reinterpret_cast<const float4*>(X + i);
    bf16x4 o;
    o[0] = f2b(v.x); o[1] = f2b(v.y); o[2] = f2b(v.z); o[3] = f2b(v.w);
    *reinterpret_cast<bf16x4*>(Xb + i) = o;
  } else {
    __shared__ float tile[32][33];
    int r = id - 4096;
    const int z = r >> 10; r &= 1023;
    const float* W; __bf16* T;
    switch (z) {
      case 0: W = W0; T = Tqkv;                       break;
      case 1: W = W1; T = Tqkv + (size_t)1024 * 1024; break;
      case 2: W = W2; T = Tqkv + (size_t)2048 * 1024; break;
      default: W = W3; T = To;                        break;
    }
    int k0 = (r & 31) * 32, n0 = (r >> 5) * 32;
    int tx = threadIdx.x & 31, ty = threadIdx.x >> 5;  // 256 thr: ty 0..7
#pragma unroll
    for (int q = ty; q < 32; q += 8)
      tile[q][tx] = W[(size_t)(k0 + q) * 1024 + n0 + tx];
    __syncthreads();
#pragma unroll
    for (int q = ty; q < 32; q += 8)
      T[(size_t)(n0 + q) * 1024 + k0 + tx] = f2b(tile[tx][q]);
  }
}

// ---------------------------------------------------------------------------
// bf16 GEMM, C = A[M,K] * Bt^T (Bt[N][K]). Tile BM x 128, BK=64.
// 256 thr = 4 waves in 2x2; wave tile (BM/2) x 64. MFMA 16x16x32.
// BK=64 single-buffer is the measured optimum (r15: -5.3us vs BK=32;
// r18: explicit dbuf/1-barrier = +4.3us REGRESSION per m99/m131-m141).
// Staging PRE-SWIZZLES the global k-column (j ^= row&7, rule #21/m173) and
// the read applies the same XOR -- full 32-bank spread.
// SCALE_Q: output x 0.18033688 (= 0.125 * log2(e)) for cols < 1024: attention
// scores land in the exp2 domain.
// VSPLIT: cols >= 2048 (V projection) written TRANSPOSED into vt[..][s].
// ---------------------------------------------------------------------------
template <int BM, bool OUT_BF16, bool SCALE_Q, bool VSPLIT>
__global__ __launch_bounds__(256) void gemm_bt(const __bf16* __restrict__ A,
                                               const __bf16* __restrict__ Bt,
                                               void* __restrict__ Cout,
                                               __bf16* __restrict__ vt,
                                               int M, int N, int K) {
  constexpr int MI = BM / 32;  // m-frags per wave
  __shared__ __align__(16) __bf16 As[BM * 64];
  __shared__ __align__(16) __bf16 Bs[128 * 64];
  const int t = threadIdx.x;
  const int lane = t & 63, w = t >> 6;
  const int g = lane >> 4, l15 = lane & 15;
  const int m0 = blockIdx.x * BM, n0 = blockIdx.y * 128;
  const int wr = w >> 1, wc = w & 1;
  const int xg = l15 & 7;  // read-side row XOR ((..+mi*16+l15)&7 == l15&7)

  f32x4 acc[MI][4];
#pragma unroll
  for (int i = 0; i < MI; i++)
#pragma unroll
    for (int j = 0; j < 4; j++) acc[i][j] = {0.f, 0.f, 0.f, 0.f};

  for (int k0 = 0; k0 < K; k0 += 64) {
    __syncthreads();
#pragma unroll
    for (int c = t; c < BM * 8; c += 256)  // A tile [BM][64], src pre-swizzled
      GLOAD_LDS16(A + (size_t)(m0 + (c >> 3)) * K + k0 + (((c & 7) ^ ((c >> 3) & 7)) * 8),
                  As + c * 8);
#pragma unroll
    for (int c = t; c < 1024; c += 256)    // Bt tile [128][64]
      GLOAD_LDS16(Bt + (size_t)(n0 + (c >> 3)) * K + k0 + (((c & 7) ^ ((c >> 3) & 7)) * 8),
                  Bs + c * 8);
    __syncthreads();

#pragma unroll
    for (int ks = 0; ks < 2; ks++) {
      bf16x8 af[MI], bfr[4];
      const int co = ((ks * 4 + g) ^ xg) * 8;
#pragma unroll
      for (int mi = 0; mi < MI; mi++)
        af[mi] = *reinterpret_cast<const bf16x8*>(As + (wr * (BM / 2) + mi * 16 + l15) * 64 + co);
#pragma unroll
      for (int ni = 0; ni < 4; ni++)
        bfr[ni] = *reinterpret_cast<const bf16x8*>(Bs + (wc * 64 + ni * 16 + l15) * 64 + co);
#pragma unroll
      for (int mi = 0; mi < MI; mi++)
#pragma unroll
        for (int ni = 0; ni < 4; ni++)
          acc[mi][ni] = __builtin_amdgcn_mfma_f32_16x16x32_bf16(af[mi], bfr[ni], acc[mi][ni], 0, 0, 0);
    }
  }

#pragma unroll
  for (int mi = 0; mi < MI; mi++)
#pragma unroll
    for (int ni = 0; ni < 4; ni++) {
      int row = m0 + wr * (BM / 2) + mi * 16 + g * 4;
      int col = n0 + wc * 64 + ni * 16 + l15;
      if (VSPLIT && col >= 2048) {  // V projection -> transposed store
        int hd = col - 2048;
        int bb = row >> 11, ss = row & 2047;
        bf16x4 v4;
#pragma unroll
        for (int r = 0; r < 4; r++) v4[r] = f2b(acc[mi][ni][r]);
        *reinterpret_cast<bf16x4*>(vt + ((size_t)((bb * 16 + (hd >> 6)) * 64 + (hd & 63))) * 2048 + ss) = v4;
      } else {
#pragma unroll
        for (int r = 0; r < 4; r++) {
          float v = acc[mi][ni][r];
          if (SCALE_Q && col < 1024) v *= 0.18033688011112042f;  // 0.125*log2(e)
          if (OUT_BF16)
            ((__bf16*)Cout)[(size_t)(row + r) * N + col] = f2b(v);
          else
            ((float*)Cout)[(size_t)(row + r) * N + col] = v;
        }
      }
    }
}

// ---------------------------------------------------------------------------
// Causal flash attention, LDS-shared K/V, KVBLK=64, member-per-block.
// r19 core with TWO changes for 4 blocks/CU:
//  1. P_lds [4][16][72] -> [4][16][64] with a 16B-chunk XOR swizzle
//     (write chunk (2nb+(g>>1))^(l15&7), read chunk g^(l15&7); same
//     phase-level bank profile as the padded layout). LDS total = 40960B
//     EXACTLY -> 4 resident blocks/CU (was 41984 -> 3).
//  2. Static 4-batch balanced mapping: batch = id>>8; q = (id>>5)&7;
//     mi = {31-q, 16+q, 15-q, q}[batch]. Any CU's 4 co-resident blocks
//     (one per batch under in-order dispatch) sum to EXACTLY 66 KV-units
//     -- needed because 4-resident leaves zero backfill for dynamic LPT.
// Softmax in exp2 domain via __builtin_amdgcn_exp2f (raw v_exp_f32; library
// exp2f is OCML slow-path -- r15 regression). Q pre-scaled 0.125*log2e.
// K[64][64] + V^T[64][64] double-buffered in LDS (reg-staged, XOR-swizzle
// chunk^=(row&7): loads issued BEFORE compute, ds_writes after = T14 split).
// Swapped QK^T (D[kv][q], lane-local softmax, M=1). T5 setprio on MFMA.
// launch_bounds min-waves 2 (r5: 4 -> spill). r12 lesson: no global_load_lds
// prefetch mixed with same-iter vector loads; no scattered-L2 V reads.
// ---------------------------------------------------------------------------
__global__ __launch_bounds__(256, 2) void attn_fwd(const __bf16* __restrict__ QKV,
                                                   const __bf16* __restrict__ Vt,
                                                   __bf16* __restrict__ ctx) {
  const int id = blockIdx.x;
  const int batch = id >> 8;                    // 0..3
  const int c = id & 255;
  const int bh = (c & 7) * 4 + ((c >> 3) & 3);
  const int q8 = (c >> 5) & 7;                  // 0..7
  int mi;
  switch (batch) {                              // per-CU Tm sums = 66
    case 0:  mi = 31 - q8; break;
    case 1:  mi = 16 + q8; break;
    case 2:  mi = 15 - q8; break;
    default: mi = q8;      break;
  }
  const int b = bh >> 4, h = bh & 15;
  const int tid = threadIdx.x, lane = tid & 63, w = tid >> 6;
  const int g = lane >> 4, l15 = lane & 15;

  __shared__ __align__(16) __bf16 Ks[2][64 * 64];
  __shared__ __align__(16) __bf16 Vs[2][64 * 64];
  __shared__ __align__(16) __bf16 P_lds[4][16][64];  // chunk-XOR swizzled

  const __bf16* Qg  = QKV + (size_t)b * SEQ * QKVN + h * 64;
  const __bf16* Kg  = Qg + 1024;
  const __bf16* VtH = Vt + (size_t)bh * 64 * 2048;
  __bf16* Cg = ctx + (size_t)b * SEQ * 1024 + h * 64;

  const int r0 = tid >> 3, j0 = tid & 7;
  const int r1 = r0 + 32;
  const int ls0 = r0 * 64 + ((j0 ^ (r0 & 7)) * 8);
  const int ls1 = r1 * 64 + ((j0 ^ (r1 & 7)) * 8);
  const size_t gk0 = (size_t)r0 * QKVN + j0 * 8;
  const size_t gk1 = (size_t)r1 * QKVN + j0 * 8;
  const size_t gv0 = (size_t)r0 * 2048 + j0 * 8;
  const size_t gv1 = (size_t)r1 * 2048 + j0 * 8;
  const int xw = l15 & 7;  // read-side row XOR ((nb*16+l15)&7 == l15&7)

  const int qw = mi * 64 + 16 * w;              // wave's 16 rows
  const int Tm = mi + 1;

  // Q fragments: qf[ks][j] = Q[qw+l15][ks*32+g*8+j]
  bf16x8 qf[2];
#pragma unroll
  for (int ks = 0; ks < 2; ks++)
    qf[ks] = *reinterpret_cast<const bf16x8*>(
        Qg + (size_t)(qw + l15) * QKVN + ks * 32 + g * 8);

  f32x4 acco[4];
  float mrun = -1e30f, lrun = 0.f;
#pragma unroll
  for (int nd = 0; nd < 4; nd++) acco[nd] = {0.f, 0.f, 0.f, 0.f};

  // prologue: stage tile 0 into buffer 0
  {
    bf16x8 ka = *reinterpret_cast<const bf16x8*>(Kg + gk0);
    bf16x8 kb = *reinterpret_cast<const bf16x8*>(Kg + gk1);
    bf16x8 va = *reinterpret_cast<const bf16x8*>(VtH + gv0);
    bf16x8 vc = *reinterpret_cast<const bf16x8*>(VtH + gv1);
    *reinterpret_cast<bf16x8*>(Ks[0] + ls0) = ka;
    *reinterpret_cast<bf16x8*>(Ks[0] + ls1) = kb;
    *reinterpret_cast<bf16x8*>(Vs[0] + ls0) = va;
    *reinterpret_cast<bf16x8*>(Vs[0] + ls1) = vc;
  }
  __syncthreads();

  for (int it = 0; it < Tm; ++it) {
    const int cur = it & 1, nxt = cur ^ 1;
    const bool hn = (it + 1 < Tm);
    bf16x8 ka, kb, va, vc;
    if (hn) {  // issue next tile's loads early (T14 split)
      const size_t kvn = (size_t)(it + 1) * 64;
      ka = *reinterpret_cast<const bf16x8*>(Kg + kvn * QKVN + gk0);
      kb = *reinterpret_cast<const bf16x8*>(Kg + kvn * QKVN + gk1);
      va = *reinterpret_cast<const bf16x8*>(VtH + kvn + gv0);
      vc = *reinterpret_cast<const bf16x8*>(VtH + kvn + gv1);
    }

    {
      const int kv0 = it * 64;
      const bool diag = (it == Tm - 1);
      const __bf16* Kc = Ks[cur];
      const __bf16* Vc = Vs[cur];

      // fragments from LDS (swizzled)
      bf16x8 kf[4][2], vb[4][2];
#pragma unroll
      for (int nb = 0; nb < 4; nb++) {
        const int row = (nb * 16 + l15) * 64;
#pragma unroll
        for (int ks = 0; ks < 2; ks++) {
          const int co = ((ks * 4 + g) ^ xw) * 8;
          kf[nb][ks] = *reinterpret_cast<const bf16x8*>(Kc + row + co);
          vb[nb][ks] = *reinterpret_cast<const bf16x8*>(Vc + row + co);
        }
      }

      // ---- QK^T (swapped): accS[nb], D[kv][q], q = qw+l15
      f32x4 accS[4];
#pragma unroll
      for (int nb = 0; nb < 4; nb++) accS[nb] = {0.f, 0.f, 0.f, 0.f};
      __builtin_amdgcn_s_setprio(1);
#pragma unroll
      for (int nb = 0; nb < 4; nb++) {
        accS[nb] = __builtin_amdgcn_mfma_f32_16x16x32_bf16(kf[nb][0], qf[0], accS[nb], 0, 0, 0);
        accS[nb] = __builtin_amdgcn_mfma_f32_16x16x32_bf16(kf[nb][1], qf[1], accS[nb], 0, 0, 0);
      }
      __builtin_amdgcn_s_setprio(0);

      // ---- causal mask (diagonal tile only)
      if (diag) {
        const int qi = qw + l15;
#pragma unroll
        for (int nb = 0; nb < 4; nb++)
#pragma unroll
          for (int r = 0; r < 4; r++) {
            int kvi = kv0 + nb * 16 + g * 4 + r;
            if (kvi > qi) accS[nb][r] = -1e30f;
          }
      }

      // ---- online softmax (exp2 domain, raw v_exp_f32), defer-max
      {
        float a0 = fmaxf(fmaxf(accS[0][0], accS[0][1]), accS[0][2]);
        float a1 = fmaxf(fmaxf(accS[0][3], accS[1][0]), accS[1][1]);
        float a2 = fmaxf(fmaxf(accS[1][2], accS[1][3]), accS[2][0]);
        float a3 = fmaxf(fmaxf(accS[2][1], accS[2][2]), accS[2][3]);
        float a4 = fmaxf(fmaxf(accS[3][0], accS[3][1]), accS[3][2]);
        float pmax = fmaxf(fmaxf(fmaxf(a0, a1), a2),
                           fmaxf(fmaxf(a3, a4), accS[3][3]));
        pmax = fmaxf(pmax, __shfl_xor(pmax, 16));
        pmax = fmaxf(pmax, __shfl_xor(pmax, 32));
        if (!__all(pmax <= mrun + 11.5416f)) {  // 8 * log2(e)
          float mnew = fmaxf(mrun, pmax);
          float corr = __builtin_amdgcn_exp2f(mrun - mnew);
          mrun = mnew;
          lrun *= corr;
#pragma unroll
          for (int r = 0; r < 4; r++) {
            float cr = __shfl(corr, (g << 4) + (g << 2) + r);
#pragma unroll
            for (int nd = 0; nd < 4; nd++) acco[nd][r] *= cr;
          }
        }
        float lsum = 0.f;
#pragma unroll
        for (int nb = 0; nb < 4; nb++) {
          bf16x4 pk;
#pragma unroll
          for (int r = 0; r < 4; r++) {
            float pv = __builtin_amdgcn_exp2f(accS[nb][r] - mrun);
            lsum += pv;
            pk[r] = (__bf16)pv;
          }
          // swizzled P write: chunk (2nb+(g>>1)) ^ (l15&7), half (g&1)
          const int pc = (((2 * nb + (g >> 1)) ^ xw) * 8) + (g & 1) * 4;
          *reinterpret_cast<bf16x4*>(&P_lds[w][l15][pc]) = pk;
        }
        lsum += __shfl_xor(lsum, 16);
        lsum += __shfl_xor(lsum, 32);
        lrun += lsum;
      }

      // ---- PV: O[q][d] += P[q][kv] * V[kv][d]
      {
        bf16x8 pa0 = *reinterpret_cast<const bf16x8*>(&P_lds[w][l15][(g ^ xw) * 8]);
        bf16x8 pa1 = *reinterpret_cast<const bf16x8*>(&P_lds[w][l15][((4 + g) ^ xw) * 8]);
        __builtin_amdgcn_s_setprio(1);
#pragma unroll
        for (int nd = 0; nd < 4; nd++) {
          acco[nd] = __builtin_amdgcn_mfma_f32_16x16x32_bf16(pa0, vb[nd][0], acco[nd], 0, 0, 0);
          acco[nd] = __builtin_amdgcn_mfma_f32_16x16x32_bf16(pa1, vb[nd][1], acco[nd], 0, 0, 0);
        }
        __builtin_amdgcn_s_setprio(0);
      }
    }

    if (hn) {  // write staged regs to the other buffer
      *reinterpret_cast<bf16x8*>(Ks[nxt] + ls0) = ka;
      *reinterpret_cast<bf16x8*>(Ks[nxt] + ls1) = kb;
      *reinterpret_cast<bf16x8*>(Vs[nxt] + ls0) = va;
      *reinterpret_cast<bf16x8*>(Vs[nxt] + ls1) = vc;
    }
    __syncthreads();
  }

  // epilogue: ctx = O / l for this wave's 16 rows
  {
    float inv = 1.0f / lrun;
#pragma unroll
    for (int r = 0; r < 4; r++) {
      float ir = __shfl(inv, (g << 4) + (g << 2) + r);
      int qrow = qw + g * 4 + r;
#pragma unroll
      for (int nd = 0; nd < 4; nd++)
        Cg[(size_t)qrow * 1024 + nd * 16 + l15] = (__bf16)(acco[nd][r] * ir);
    }
  }
}

// ---------------------------------------------------------------------------
extern "C" void kernel_launch(void* const* d_in, const int* in_sizes, int n_in,
                              void* d_out, int out_size, void* d_ws, size_t ws_size,
                              hipStream_t stream) {
  const float* X  = (const float*)d_in[0];
  const float* Wq = (const float*)d_in[1];
  const float* Wk = (const float*)d_in[2];
  const float* Wv = (const float*)d_in[3];
  const float* Wo = (const float*)d_in[4];
  float* out = (float*)d_out;

  uint8_t* ws = (uint8_t*)d_ws;
  size_t off = 0;
  const size_t actBytes = (size_t)MROWS * 1024 * 2;          // 8 MB
  __bf16* Xb    = (__bf16*)(ws + off); off += actBytes;      // freed after QKV gemm
  __bf16* WqkvT = (__bf16*)(ws + off); off += (size_t)QKVN * 1024 * 2;
  __bf16* WoT   = (__bf16*)(ws + off); off += (size_t)1024 * 1024 * 2;
  __bf16* QKV   = (__bf16*)(ws + off); off += (size_t)MROWS * QKVN * 2;
  __bf16* Vt    = (__bf16*)(ws + off); off += actBytes;
  __bf16* Cb    = Xb;  // alias: X dead after QKV projection

  // 1) fused cast + weight transpose
  prep<<<dim3(8192), dim3(256), 0, stream>>>(X, Wq, Wk, Wv, Wo, Xb, WqkvT, WoT);

  // 2) fused QKV projection (Q pre-scaled by 0.125*log2e; V transposed to Vt)
  gemm_bt<128, true, true, true><<<dim3(MROWS / 128, QKVN / 128), dim3(256), 0, stream>>>(
      Xb, WqkvT, QKV, Vt, MROWS, QKVN, EMB);

  // 3) causal flash attention (4 blocks/CU, statically balanced batches)
  attn_fwd<<<dim3(1024), dim3(256), 0, stream>>>(QKV, Vt, Cb);

  // 4) output projection (fp32 out), 64x128 tiles (512 blocks, 2/CU)
  gemm_bt<64, false, false, false><<<dim3(MROWS / 64, PROJ / 128), dim3(256), 0, stream>>>(
      Cb, WoT, out, nullptr, MROWS, PROJ, PROJ);
}